// Round 11
// baseline (585.573 us; speedup 1.0000x reference)
//
#include <hip/hip_runtime.h>
#include <hip/hip_fp16.h>
#include <cstdint>
#include <cstddef>
#include <math.h>

// Problem constants (match reference: B,C,N,K = 16,64,2048,20)
#define BB 16
#define CC 64
#define NN 2048
#define KK 20
#define K2 14   // ceil(20*2/3)
#define TQ 16   // queries per block in knn kernel (one per wave, 16 waves)
#define NC 26   // candidate count (margin over K=20 for approx->fp64 rank safety)
#define SPH 2052 // fp16 pd row stride (halves)

// native clang vector type for nontemporal builtin (HIP float4 is a class)
typedef float nfloat4 __attribute__((ext_vector_type(4)));

// ---------------------------------------------------------------------------
// prep: xt[b][n][c] = x[b][c][n]  (fp32, 256B rows), plus norms in fp64+fp32.
// ---------------------------------------------------------------------------
__global__ __launch_bounds__(256) void prep_kernel(const float* __restrict__ x,
                                                   float* __restrict__ xt,
                                                   float* __restrict__ xxf,
                                                   double* __restrict__ xxd) {
    __shared__ float s_t[64][65];
    int b = blockIdx.x >> 5;
    int n0 = (blockIdx.x & 31) * 64;
    const float* xb = x + (size_t)b * CC * NN;
    int tid = threadIdx.x;
    int cq = tid >> 6;
    int nl = tid & 63;

#pragma unroll
    for (int r = 0; r < 16; ++r) {
        int c = r * 4 + cq;
        s_t[c][nl] = xb[c * NN + n0 + nl];
    }
    __syncthreads();

#pragma unroll
    for (int r = 0; r < 16; ++r) {
        int n = r * 4 + cq;
        xt[((size_t)b * NN + n0 + n) * CC + nl] = s_t[nl][n];
    }

    if (tid < 64) {
        double s = 0.0;
#pragma unroll
        for (int c = 0; c < CC; ++c) {
            double v = (double)s_t[c][tid];
            s += v * v;
        }
        xxd[b * NN + n0 + tid] = s;
        xxf[b * NN + n0 + tid] = (float)s;
    }
}

// ---------------------------------------------------------------------------
// knn v11: v10 (TQ=16, fp16 pd, full occupancy) plus:
//  (1) fill q/x DOUBLE-BUFFER: next-iter scalar q load + xv load issued
//      before the current FMA block -- breaks the per-iter lgkmcnt
//      serialization (q addr strides 8KB -> K$ always misses, ~200cy).
//      q lives in SGPRs (uniform addr), so VGPR stays under the 64 cap.
//  (2) phase-3 pair-lane fp64 refine: lanes 2t,2t+1 split candidate t's
//      64-ch dot (32 ch each), combine via shfl_xor(1) -- 52/64 lanes
//      active, half the fp64 chain and loads.
// Phases 2 and all bitonics byte-identical to v10.
// ---------------------------------------------------------------------------
__global__ __launch_bounds__(1024, 8) void knn_kernel(const float* __restrict__ x,
                                                      const float* __restrict__ xt,
                                                      const float* __restrict__ xxf,
                                                      const double* __restrict__ xxd,
                                                      int* __restrict__ idx_ws,
                                                      float* __restrict__ idx_out) {
    __shared__ __half s_pd[TQ][SPH];               // 65.7 KiB fp16 pd rows
    __shared__ __align__(16) float s_qT[TQ][CC];   // 4 KiB, [q][c] for phase 3
    __shared__ float s_sv[TQ][64];                 // survivor values (4 KiB)
    __shared__ int   s_si[TQ][64];                 // survivor indices (4 KiB)

    int tid = threadIdx.x;
    int b = blockIdx.x >> 7;                       // NN/TQ = 128 blocks/batch
    int n0 = (blockIdx.x & 127) * TQ;
    const float* xb = x + (size_t)b * CC * NN;

    {
        int c = tid >> 4, qq = tid & 15;
        s_qT[qq][c] = xb[c * NN + n0 + qq];
    }
    __syncthreads();

    // ---- phase 1: fill (thread owns 2 consecutive m for all 16 queries) ----
    {
        float xxn[TQ];
#pragma unroll
        for (int i = 0; i < TQ; i += 4) {
            float4 t = *(const float4*)(xxf + b * NN + n0 + i);   // uniform -> s_load
            xxn[i] = t.x; xxn[i + 1] = t.y; xxn[i + 2] = t.z; xxn[i + 3] = t.w;
        }

        int m = tid * 2;
        float acc[TQ][2];
#pragma unroll
        for (int q = 0; q < TQ; ++q) { acc[q][0] = 0.f; acc[q][1] = 0.f; }

        // preload c=0 (q uniform -> SGPRs; xv -> 2 VGPRs)
        float4 qA = *(const float4*)(xb + n0);
        float4 qB = *(const float4*)(xb + n0 + 4);
        float4 qC = *(const float4*)(xb + n0 + 8);
        float4 qD = *(const float4*)(xb + n0 + 12);
        float2 xv = *(const float2*)(xb + m);

        for (int c = 0; c < CC; ++c) {
            // capture current iter's operands
            float qs[TQ] = {qA.x, qA.y, qA.z, qA.w, qB.x, qB.y, qB.z, qB.w,
                            qC.x, qC.y, qC.z, qC.w, qD.x, qD.y, qD.z, qD.w};
            float2 xc = xv;
            // issue next iter's loads NOW (branchless wrap; c=63 reloads c=0)
            {
                int cn = (c + 1) & 63;
                const float* nqp = xb + cn * NN;
                qA = *(const float4*)(nqp + n0);
                qB = *(const float4*)(nqp + n0 + 4);
                qC = *(const float4*)(nqp + n0 + 8);
                qD = *(const float4*)(nqp + n0 + 12);
                xv = *(const float2*)(nqp + m);
            }
#pragma unroll
            for (int q = 0; q < TQ; ++q) {
                acc[q][0] += qs[q] * xc.x;
                acc[q][1] += qs[q] * xc.y;
            }
        }
        float2 xm2 = *(const float2*)(xxf + b * NN + m);
#pragma unroll
        for (int q = 0; q < TQ; ++q) {
            float p0 = (2.f * acc[q][0] - xxn[q]) - xm2.x;
            float p1 = (2.f * acc[q][1] - xxn[q]) - xm2.y;
            *(__half2*)(&s_pd[q][m]) = __floats2half2_rn(p0, p1);
        }
    }
    __syncthreads();

    // ---- phase 2: per-wave selection ----
    int q = tid >> 6;
    int lane = tid & 63;
    const __half* pd = &s_pd[q][0];

    float v[32];
#pragma unroll
    for (int r = 0; r < 32; ++r) v[r] = __half2float(pd[lane + (r << 6)]);

    float lmax = v[0]; int lr = 0;
#pragma unroll
    for (int r = 1; r < 32; ++r)
        if (v[r] > lmax) { lmax = v[r]; lr = r; }              // strict > : lowest idx

    // tau = 26th-largest lane-max (values-only 64-lane bitonic, descending)
    float sv = lmax;
#pragma unroll
    for (int k = 2; k <= 64; k <<= 1) {
#pragma unroll
        for (int j = k >> 1; j > 0; j >>= 1) {
            float o = __shfl_xor(sv, j);
            bool dird = ((lane & k) == 0);
            bool first = ((lane & j) == 0);
            sv = (first == dird) ? fmaxf(sv, o) : fminf(sv, o);
        }
    }
    float tau = __shfl(sv, 25);

    int cnt = 0;
#pragma unroll
    for (int r = 0; r < 32; ++r) cnt += (v[r] >= tau) ? 1 : 0;
    int incl = cnt;
#pragma unroll
    for (int off = 1; off < 64; off <<= 1) {
        int o = __shfl_up(incl, off);
        if (lane >= off) incl += o;
    }
    int S = __shfl(incl, 63);

    float fv = -INFINITY;
    int fi = 0x7fffffff;
    if (S <= 64) {
        int w = incl - cnt;
#pragma unroll
        for (int r = 0; r < 32; ++r) {
            if (v[r] >= tau) { s_sv[q][w] = v[r]; s_si[q][w] = lane + (r << 6); ++w; }
        }
        if (lane < S) { fv = s_sv[q][lane]; fi = s_si[q][lane]; }
    } else {
        // pathological (mass ties): exact iterative top-26 extraction
        for (int t = 0; t < NC; ++t) {
            float bv = lmax; int bi = lane + (lr << 6);
#pragma unroll
            for (int off = 32; off; off >>= 1) {
                float ov = __shfl_xor(bv, off);
                int oi = __shfl_xor(bi, off);
                if (ov > bv || (ov == bv && oi < bi)) { bv = ov; bi = oi; }
            }
            if (lane == t) { fv = bv; fi = bi; }
            if ((bi & 63) == lane) {
                int rsel = bi >> 6;
#pragma unroll
                for (int r = 0; r < 32; ++r) if (r == rsel) v[r] = -INFINITY;
                lmax = v[0]; lr = 0;
#pragma unroll
                for (int r = 1; r < 32; ++r)
                    if (v[r] > lmax) { lmax = v[r]; lr = r; }
            }
        }
    }

    // 64-lane bitonic sort of (fv desc, fi asc) -> lanes 0..25 = approx top-26
#pragma unroll
    for (int k = 2; k <= 64; k <<= 1) {
#pragma unroll
        for (int j = k >> 1; j > 0; j >>= 1) {
            float ov = __shfl_xor(fv, j);
            int oi = __shfl_xor(fi, j);
            bool dird = ((lane & k) == 0);
            bool first = ((lane & j) == 0);
            bool better = (fv > ov) || (fv == ov && fi < oi);
            if (better != (first == dird)) { fv = ov; fi = oi; }
        }
    }

    // ---- phase 3: fp64 refine, pair-lane split (lanes 2t,2t+1 -> cand t) ----
    int nq = n0 + q;
    int cand_l = lane >> 1;                        // candidate this lane helps
    int halfsel = lane & 1;                        // which 32-channel half
    int ci = __shfl(fi, cand_l);                   // candidate's point index
    double part = 0.0;
    if (cand_l < NC) {
        const float* crow = xt + (size_t)b * NN * CC + (size_t)ci * CC + halfsel * 32;
        const float* qrow = &s_qT[q][halfsel * 32];
        double a0 = 0.0, a1 = 0.0, a2 = 0.0, a3 = 0.0;
#pragma unroll
        for (int j = 0; j < 8; ++j) {
            float4 cv = *(const float4*)(crow + j * 4);
            float4 qv = *(const float4*)(qrow + j * 4);   // LDS b128 broadcast
            a0 = fma((double)qv.x, (double)cv.x, a0);
            a1 = fma((double)qv.y, (double)cv.y, a1);
            a2 = fma((double)qv.z, (double)cv.z, a2);
            a3 = fma((double)qv.w, (double)cv.w, a3);
        }
        part = (a0 + a1) + (a2 + a3);
    }
    part += __shfl_xor(part, 1);                   // pair total (both lanes)
    double accd = __shfl(part, lane << 1);         // lane t <- lanes 2t (t<32)

    double val = -INFINITY;
    int idxq = 0x7fffffff;
    if (lane < NC) {
        val = 2.0 * accd - xxd[b * NN + nq] - xxd[b * NN + fi];
        idxq = fi;
    }

    // 32-lane fp64 bitonic (val desc, idx asc)
#pragma unroll
    for (int k = 2; k <= 32; k <<= 1) {
#pragma unroll
        for (int j = k >> 1; j > 0; j >>= 1) {
            double ov = __shfl_xor(val, j, 32);
            int oi = __shfl_xor(idxq, j, 32);
            bool dird = ((lane & k) == 0);
            bool first = ((lane & j) == 0);
            bool better = (val > ov) || (val == ov && idxq < oi);
            if (better != (first == dird)) { val = ov; idxq = oi; }
        }
    }

    if (lane < KK) {
        size_t obase = ((size_t)b * NN + nq) * KK;
        idx_ws[obase + lane] = idxq;
        idx_out[obase + lane] = (float)(idxq + b * NN);
    }
}

// ---------------------------------------------------------------------------
// x1: mean of top-14 of 20 gathered neighbor values, written channel-major
// as x1t[b][c][n]. (sum20 - six minima)/14, order-independent.
// ---------------------------------------------------------------------------
__global__ __launch_bounds__(256) void x1_kernel(const float* __restrict__ xt,
                                                 const int* __restrict__ idx_ws,
                                                 float* __restrict__ x1t) {
    __shared__ int s_idx[16][KK];
    __shared__ float s_out[64][17];
    int tid = threadIdx.x;
    int b = blockIdx.x >> 7;
    int n0 = (blockIdx.x & 127) * 16;
    const float* xtb = xt + (size_t)b * NN * CC;

    for (int i = tid; i < 16 * KK; i += 256)
        s_idx[i / KK][i % KK] = idx_ws[((size_t)b * NN + n0) * KK + i];
    __syncthreads();

    int pl = tid >> 6, c = tid & 63;
#pragma unroll
    for (int it = 0; it < 4; ++it) {
        int nl = it * 4 + pl;
        float vals[KK];
        float sum = 0.f;
#pragma unroll
        for (int j = 0; j < KK; ++j) {
            vals[j] = xtb[(size_t)s_idx[nl][j] * CC + c];
            sum += vals[j];
        }
#pragma unroll
        for (int t = 0; t < KK - K2; ++t) {
            float worst = INFINITY;
            int wj = 0;
#pragma unroll
            for (int j = 0; j < KK; ++j)
                if (vals[j] < worst) { worst = vals[j]; wj = j; }
            sum -= worst;
            vals[wj] = INFINITY;
        }
        s_out[c][nl] = sum / (float)K2;
    }
    __syncthreads();

    int cw = tid >> 2, nw = (tid & 3) * 4;
    float4 v = make_float4(s_out[cw][nw], s_out[cw][nw + 1],
                           s_out[cw][nw + 2], s_out[cw][nw + 3]);
    *(float4*)(&x1t[((size_t)b * CC + cw) * NN + n0 + nw]) = v;
}

// ---------------------------------------------------------------------------
// feat: float4-vectorized. feature[b,ch,n,j]:
//   ch <  64: x1t[b,ch,idx[b,n,j]] - x[b,ch,n]
//   ch >= 64: x[b,ch-64,n]
// Write-only 335 MB output -> non-temporal stores.
// ---------------------------------------------------------------------------
__global__ __launch_bounds__(256) void feat_kernel(const float* __restrict__ x,
                                                   const float* __restrict__ x1t,
                                                   const int* __restrict__ idx_ws,
                                                   float* __restrict__ out) {
    int bc = blockIdx.x;
    int b = bc >> 7, ch = bc & 127;
    const float* xb = x + (size_t)b * CC * NN;
    float* o = out + (size_t)bc * NN * KK;
    const int* idxb = idx_ws + (size_t)b * NN * KK;

    if (ch < CC) {
        const float* row = x1t + ((size_t)b * CC + ch) * NN;
        const float* xr = xb + ch * NN;
        for (int it = 0; it < 40; ++it) {
            unsigned e = (it * 256 + threadIdx.x) * 4;
            int4 id4 = *(const int4*)(idxb + e);
            nfloat4 o4;
            o4.x = row[id4.x] - xr[(e    ) / KK];
            o4.y = row[id4.y] - xr[(e + 1) / KK];
            o4.z = row[id4.z] - xr[(e + 2) / KK];
            o4.w = row[id4.w] - xr[(e + 3) / KK];
            __builtin_nontemporal_store(o4, (nfloat4*)(o + e));
        }
    } else {
        const float* xr = xb + (ch - CC) * NN;
        for (int it = 0; it < 40; ++it) {
            unsigned e = (it * 256 + threadIdx.x) * 4;
            nfloat4 o4;
            o4.x = xr[(e    ) / KK];
            o4.y = xr[(e + 1) / KK];
            o4.z = xr[(e + 2) / KK];
            o4.w = xr[(e + 3) / KK];
            __builtin_nontemporal_store(o4, (nfloat4*)(o + e));
        }
    }
}

// ---------------------------------------------------------------------------
extern "C" void kernel_launch(void* const* d_in, const int* in_sizes, int n_in,
                              void* d_out, int out_size, void* d_ws, size_t ws_size,
                              hipStream_t stream) {
    const float* x = (const float*)d_in[0];   // (B, C, N) fp32
    float* out = (float*)d_out;

    char* ws = (char*)d_ws;
    float* xt   = (float*)ws;                                   // B*N*C
    float* x1t  = (float*)(ws + (size_t)8388608);               // B*C*N
    double* xxd = (double*)(ws + (size_t)16777216);             // B*N
    float* xxf  = (float*)(ws + (size_t)17039360);              // B*N
    int* idx_ws = (int*)(ws + (size_t)17170432);                // B*N*K

    float* idx_out = out + (size_t)BB * 2 * CC * NN * KK;       // idx_flat tail

    prep_kernel<<<BB * (NN / 64), 256, 0, stream>>>(x, xt, xxf, xxd);
    knn_kernel<<<BB * (NN / TQ), 1024, 0, stream>>>(x, xt, xxf, xxd, idx_ws, idx_out);
    x1_kernel<<<BB * (NN / 16), 256, 0, stream>>>(xt, idx_ws, x1t);
    feat_kernel<<<BB * 2 * CC, 256, 0, stream>>>(x, x1t, idx_ws, out);
}

// Round 12
// 574.724 us; speedup vs baseline: 1.0189x; 1.0189x over previous
//
#include <hip/hip_runtime.h>
#include <hip/hip_fp16.h>
#include <cstdint>
#include <cstddef>
#include <math.h>

// Problem constants (match reference: B,C,N,K = 16,64,2048,20)
#define BB 16
#define CC 64
#define NN 2048
#define KK 20
#define K2 14   // ceil(20*2/3)
#define TQ 16   // queries per block in knn kernel (one per wave, 16 waves)
#define NC 26   // candidate count (margin over K=20 for approx->fp64 rank safety)
#define SPH 2052 // fp16 pd row stride (halves)

// native clang vector type for nontemporal builtin (HIP float4 is a class)
typedef float nfloat4 __attribute__((ext_vector_type(4)));

// ---------------------------------------------------------------------------
// prep: xt[b][n][c] = x[b][c][n]  (fp32, 256B rows), plus norms in fp64+fp32.
// ---------------------------------------------------------------------------
__global__ __launch_bounds__(256) void prep_kernel(const float* __restrict__ x,
                                                   float* __restrict__ xt,
                                                   float* __restrict__ xxf,
                                                   double* __restrict__ xxd) {
    __shared__ float s_t[64][65];
    int b = blockIdx.x >> 5;
    int n0 = (blockIdx.x & 31) * 64;
    const float* xb = x + (size_t)b * CC * NN;
    int tid = threadIdx.x;
    int cq = tid >> 6;
    int nl = tid & 63;

#pragma unroll
    for (int r = 0; r < 16; ++r) {
        int c = r * 4 + cq;
        s_t[c][nl] = xb[c * NN + n0 + nl];
    }
    __syncthreads();

#pragma unroll
    for (int r = 0; r < 16; ++r) {
        int n = r * 4 + cq;
        xt[((size_t)b * NN + n0 + n) * CC + nl] = s_t[nl][n];
    }

    if (tid < 64) {
        double s = 0.0;
#pragma unroll
        for (int c = 0; c < CC; ++c) {
            double v = (double)s_t[c][tid];
            s += v * v;
        }
        xxd[b * NN + n0 + tid] = s;
        xxf[b * NN + n0 + tid] = (float)s;
    }
}

// ---------------------------------------------------------------------------
// knn v12 = v10 (fastest base: TQ=16, fp16 pd, scalar-q fill, full occupancy)
// + FUSED x1 tail: wave q already holds its query's top-20 indices and just
// pulled the candidate rows through L1 in phase 3 -- so compute
// x1[c] = (sum of top-14 of 20 neighbor values)/14 right here (identical op
// order to the old x1_kernel -> bit-identical output) and delete x1_kernel.
// ---------------------------------------------------------------------------
__global__ __launch_bounds__(1024, 8) void knn_kernel(const float* __restrict__ x,
                                                      const float* __restrict__ xt,
                                                      const float* __restrict__ xxf,
                                                      const double* __restrict__ xxd,
                                                      int* __restrict__ idx_ws,
                                                      float* __restrict__ idx_out,
                                                      float* __restrict__ x1t) {
    __shared__ __half s_pd[TQ][SPH];               // 65.7 KiB fp16 pd rows
    __shared__ __align__(16) float s_qT[TQ][CC];   // 4 KiB, [q][c] for phase 3
    __shared__ float s_sv[TQ][64];                 // survivor values (4 KiB)
    __shared__ int   s_si[TQ][64];                 // survivor indices (4 KiB)

    int tid = threadIdx.x;
    int b = blockIdx.x >> 7;                       // NN/TQ = 128 blocks/batch
    int n0 = (blockIdx.x & 127) * TQ;
    const float* xb = x + (size_t)b * CC * NN;

    {
        int c = tid >> 4, qq = tid & 15;
        s_qT[qq][c] = xb[c * NN + n0 + qq];
    }
    __syncthreads();

    // ---- phase 1: fill (thread owns 2 consecutive m for all 16 queries) ----
    {
        float xxn[TQ];
#pragma unroll
        for (int i = 0; i < TQ; i += 4) {
            float4 t = *(const float4*)(xxf + b * NN + n0 + i);   // uniform -> s_load
            xxn[i] = t.x; xxn[i + 1] = t.y; xxn[i + 2] = t.z; xxn[i + 3] = t.w;
        }

        int m = tid * 2;
        float acc[TQ][2];
#pragma unroll
        for (int q = 0; q < TQ; ++q) { acc[q][0] = 0.f; acc[q][1] = 0.f; }

        for (int c = 0; c < CC; ++c) {
            float2 xv = *(const float2*)(xb + c * NN + m);
            // wave-uniform address -> scalar loads (constant cache, no LDS)
            const float* qp = xb + c * NN + n0;
            float qs[TQ];
#pragma unroll
            for (int i = 0; i < TQ; i += 4) {
                float4 t = *(const float4*)(qp + i);
                qs[i] = t.x; qs[i + 1] = t.y; qs[i + 2] = t.z; qs[i + 3] = t.w;
            }
#pragma unroll
            for (int q = 0; q < TQ; ++q) {
                acc[q][0] += qs[q] * xv.x;
                acc[q][1] += qs[q] * xv.y;
            }
        }
        float2 xm2 = *(const float2*)(xxf + b * NN + m);
#pragma unroll
        for (int q = 0; q < TQ; ++q) {
            float p0 = (2.f * acc[q][0] - xxn[q]) - xm2.x;
            float p1 = (2.f * acc[q][1] - xxn[q]) - xm2.y;
            *(__half2*)(&s_pd[q][m]) = __floats2half2_rn(p0, p1);
        }
    }
    __syncthreads();

    // ---- phase 2: per-wave selection ----
    int q = tid >> 6;
    int lane = tid & 63;
    const __half* pd = &s_pd[q][0];

    float v[32];
#pragma unroll
    for (int r = 0; r < 32; ++r) v[r] = __half2float(pd[lane + (r << 6)]);

    float lmax = v[0]; int lr = 0;
#pragma unroll
    for (int r = 1; r < 32; ++r)
        if (v[r] > lmax) { lmax = v[r]; lr = r; }              // strict > : lowest idx

    // tau = 26th-largest lane-max (values-only 64-lane bitonic, descending)
    float sv = lmax;
#pragma unroll
    for (int k = 2; k <= 64; k <<= 1) {
#pragma unroll
        for (int j = k >> 1; j > 0; j >>= 1) {
            float o = __shfl_xor(sv, j);
            bool dird = ((lane & k) == 0);
            bool first = ((lane & j) == 0);
            sv = (first == dird) ? fmaxf(sv, o) : fminf(sv, o);
        }
    }
    float tau = __shfl(sv, 25);

    int cnt = 0;
#pragma unroll
    for (int r = 0; r < 32; ++r) cnt += (v[r] >= tau) ? 1 : 0;
    int incl = cnt;
#pragma unroll
    for (int off = 1; off < 64; off <<= 1) {
        int o = __shfl_up(incl, off);
        if (lane >= off) incl += o;
    }
    int S = __shfl(incl, 63);

    float fv = -INFINITY;
    int fi = 0x7fffffff;
    if (S <= 64) {
        int w = incl - cnt;
#pragma unroll
        for (int r = 0; r < 32; ++r) {
            if (v[r] >= tau) { s_sv[q][w] = v[r]; s_si[q][w] = lane + (r << 6); ++w; }
        }
        if (lane < S) { fv = s_sv[q][lane]; fi = s_si[q][lane]; }
    } else {
        // pathological (mass ties): exact iterative top-26 extraction
        for (int t = 0; t < NC; ++t) {
            float bv = lmax; int bi = lane + (lr << 6);
#pragma unroll
            for (int off = 32; off; off >>= 1) {
                float ov = __shfl_xor(bv, off);
                int oi = __shfl_xor(bi, off);
                if (ov > bv || (ov == bv && oi < bi)) { bv = ov; bi = oi; }
            }
            if (lane == t) { fv = bv; fi = bi; }
            if ((bi & 63) == lane) {
                int rsel = bi >> 6;
#pragma unroll
                for (int r = 0; r < 32; ++r) if (r == rsel) v[r] = -INFINITY;
                lmax = v[0]; lr = 0;
#pragma unroll
                for (int r = 1; r < 32; ++r)
                    if (v[r] > lmax) { lmax = v[r]; lr = r; }
            }
        }
    }

    // 64-lane bitonic sort of (fv desc, fi asc) -> lanes 0..25 = approx top-26
#pragma unroll
    for (int k = 2; k <= 64; k <<= 1) {
#pragma unroll
        for (int j = k >> 1; j > 0; j >>= 1) {
            float ov = __shfl_xor(fv, j);
            int oi = __shfl_xor(fi, j);
            bool dird = ((lane & k) == 0);
            bool first = ((lane & j) == 0);
            bool better = (fv > ov) || (fv == ov && fi < oi);
            if (better != (first == dird)) { fv = ov; fi = oi; }
        }
    }

    // ---- phase 3: fp64 refine (direct global candidate rows, L2-hot) ----
    int nq = n0 + q;
    double accd = 0.0;
    if (lane < NC) {
        const float* crow = xt + (size_t)b * NN * CC + (size_t)fi * CC;
        const float* qrow = &s_qT[q][0];
        double a0 = 0.0, a1 = 0.0, a2 = 0.0, a3 = 0.0;
#pragma unroll
        for (int j = 0; j < 16; ++j) {
            float4 cv = *(const float4*)(crow + j * 4);
            float4 qv = *(const float4*)(qrow + j * 4);   // LDS b128 broadcast
            a0 = fma((double)qv.x, (double)cv.x, a0);
            a1 = fma((double)qv.y, (double)cv.y, a1);
            a2 = fma((double)qv.z, (double)cv.z, a2);
            a3 = fma((double)qv.w, (double)cv.w, a3);
        }
        accd = (a0 + a1) + (a2 + a3);
    }

    double val = -INFINITY;
    int idxq = 0x7fffffff;
    if (lane < NC) {
        val = 2.0 * accd - xxd[b * NN + nq] - xxd[b * NN + fi];
        idxq = fi;
    }

    // 32-lane fp64 bitonic (val desc, idx asc)
#pragma unroll
    for (int k = 2; k <= 32; k <<= 1) {
#pragma unroll
        for (int j = k >> 1; j > 0; j >>= 1) {
            double ov = __shfl_xor(val, j, 32);
            int oi = __shfl_xor(idxq, j, 32);
            bool dird = ((lane & k) == 0);
            bool first = ((lane & j) == 0);
            bool better = (val > ov) || (val == ov && idxq < oi);
            if (better != (first == dird)) { val = ov; idxq = oi; }
        }
    }

    if (lane < KK) {
        size_t obase = ((size_t)b * NN + nq) * KK;
        idx_ws[obase + lane] = idxq;
        idx_out[obase + lane] = (float)(idxq + b * NN);
        s_si[q][lane] = idxq;                      // stash top-20 for fused x1
    }

    // ---- fused x1: per-channel mean of top-14 of the 20 neighbor values ----
    // Same op order as the old x1_kernel -> bit-identical output. Rows are
    // L1-hot (phase 3 just read them); gathers are coalesced 256B per j.
    {
        const float* xtb = xt + (size_t)b * NN * CC;
        float vals[KK];
        float sum = 0.f;
#pragma unroll
        for (int j = 0; j < KK; ++j) {
            int ij = s_si[q][j];                   // per-wave LDS broadcast
            vals[j] = xtb[(size_t)ij * CC + lane]; // lane c reads channel c
            sum += vals[j];
        }
#pragma unroll
        for (int t = 0; t < KK - K2; ++t) {
            float worst = INFINITY;
            int wj = 0;
#pragma unroll
            for (int j = 0; j < KK; ++j)
                if (vals[j] < worst) { worst = vals[j]; wj = j; }
            sum -= worst;
#pragma unroll
            for (int j = 0; j < KK; ++j)
                if (j == wj) vals[j] = INFINITY;
        }
        x1t[((size_t)b * CC + lane) * NN + nq] = sum / (float)K2;
    }
}

// ---------------------------------------------------------------------------
// feat: float4-vectorized. feature[b,ch,n,j]:
//   ch <  64: x1t[b,ch,idx[b,n,j]] - x[b,ch,n]
//   ch >= 64: x[b,ch-64,n]
// Write-only 335 MB output -> non-temporal stores.
// ---------------------------------------------------------------------------
__global__ __launch_bounds__(256) void feat_kernel(const float* __restrict__ x,
                                                   const float* __restrict__ x1t,
                                                   const int* __restrict__ idx_ws,
                                                   float* __restrict__ out) {
    int bc = blockIdx.x;
    int b = bc >> 7, ch = bc & 127;
    const float* xb = x + (size_t)b * CC * NN;
    float* o = out + (size_t)bc * NN * KK;
    const int* idxb = idx_ws + (size_t)b * NN * KK;

    if (ch < CC) {
        const float* row = x1t + ((size_t)b * CC + ch) * NN;
        const float* xr = xb + ch * NN;
        for (int it = 0; it < 40; ++it) {
            unsigned e = (it * 256 + threadIdx.x) * 4;
            int4 id4 = *(const int4*)(idxb + e);
            nfloat4 o4;
            o4.x = row[id4.x] - xr[(e    ) / KK];
            o4.y = row[id4.y] - xr[(e + 1) / KK];
            o4.z = row[id4.z] - xr[(e + 2) / KK];
            o4.w = row[id4.w] - xr[(e + 3) / KK];
            __builtin_nontemporal_store(o4, (nfloat4*)(o + e));
        }
    } else {
        const float* xr = xb + (ch - CC) * NN;
        for (int it = 0; it < 40; ++it) {
            unsigned e = (it * 256 + threadIdx.x) * 4;
            nfloat4 o4;
            o4.x = xr[(e    ) / KK];
            o4.y = xr[(e + 1) / KK];
            o4.z = xr[(e + 2) / KK];
            o4.w = xr[(e + 3) / KK];
            __builtin_nontemporal_store(o4, (nfloat4*)(o + e));
        }
    }
}

// ---------------------------------------------------------------------------
extern "C" void kernel_launch(void* const* d_in, const int* in_sizes, int n_in,
                              void* d_out, int out_size, void* d_ws, size_t ws_size,
                              hipStream_t stream) {
    const float* x = (const float*)d_in[0];   // (B, C, N) fp32
    float* out = (float*)d_out;

    char* ws = (char*)d_ws;
    float* xt   = (float*)ws;                                   // B*N*C
    float* x1t  = (float*)(ws + (size_t)8388608);               // B*C*N
    double* xxd = (double*)(ws + (size_t)16777216);             // B*N
    float* xxf  = (float*)(ws + (size_t)17039360);              // B*N
    int* idx_ws = (int*)(ws + (size_t)17170432);                // B*N*K

    float* idx_out = out + (size_t)BB * 2 * CC * NN * KK;       // idx_flat tail

    prep_kernel<<<BB * (NN / 64), 256, 0, stream>>>(x, xt, xxf, xxd);
    knn_kernel<<<BB * (NN / TQ), 1024, 0, stream>>>(x, xt, xxf, xxd, idx_ws, idx_out, x1t);
    feat_kernel<<<BB * 2 * CC, 256, 0, stream>>>(x, x1t, idx_ws, out);
}

// Round 13
// 530.575 us; speedup vs baseline: 1.1037x; 1.0832x over previous
//
#include <hip/hip_runtime.h>
#include <hip/hip_fp16.h>
#include <cstdint>
#include <cstddef>
#include <math.h>

// Problem constants (match reference: B,C,N,K = 16,64,2048,20)
#define BB 16
#define CC 64
#define NN 2048
#define KK 20
#define K2 14   // ceil(20*2/3)
#define TQ 16   // queries per block in knn kernel (one per wave, 16 waves)
#define NC 26   // candidate count (margin over K=20 for approx->fp64 rank safety)
#define SPH 2052 // fp16 pd row stride (halves)

// native clang vector type for nontemporal builtin (HIP float4 is a class)
typedef float nfloat4 __attribute__((ext_vector_type(4)));

// ---------------------------------------------------------------------------
// prep: xt[b][n][c] = x[b][c][n]  (fp32, 256B rows), plus norms in fp64+fp32.
// ---------------------------------------------------------------------------
__global__ __launch_bounds__(256) void prep_kernel(const float* __restrict__ x,
                                                   float* __restrict__ xt,
                                                   float* __restrict__ xxf,
                                                   double* __restrict__ xxd) {
    __shared__ float s_t[64][65];
    int b = blockIdx.x >> 5;
    int n0 = (blockIdx.x & 31) * 64;
    const float* xb = x + (size_t)b * CC * NN;
    int tid = threadIdx.x;
    int cq = tid >> 6;
    int nl = tid & 63;

#pragma unroll
    for (int r = 0; r < 16; ++r) {
        int c = r * 4 + cq;
        s_t[c][nl] = xb[c * NN + n0 + nl];
    }
    __syncthreads();

#pragma unroll
    for (int r = 0; r < 16; ++r) {
        int n = r * 4 + cq;
        xt[((size_t)b * NN + n0 + n) * CC + nl] = s_t[nl][n];
    }

    if (tid < 64) {
        double s = 0.0;
#pragma unroll
        for (int c = 0; c < CC; ++c) {
            double v = (double)s_t[c][tid];
            s += v * v;
        }
        xxd[b * NN + n0 + tid] = s;
        xxf[b * NN + n0 + tid] = (float)s;
    }
}

// ---------------------------------------------------------------------------
// knn v12 (unchanged from round 12's passing 574.7us version): TQ=16, fp16 pd,
// scalar-q fill, full occupancy, fused x1 tail.
// ---------------------------------------------------------------------------
__global__ __launch_bounds__(1024, 8) void knn_kernel(const float* __restrict__ x,
                                                      const float* __restrict__ xt,
                                                      const float* __restrict__ xxf,
                                                      const double* __restrict__ xxd,
                                                      int* __restrict__ idx_ws,
                                                      float* __restrict__ idx_out,
                                                      float* __restrict__ x1t) {
    __shared__ __half s_pd[TQ][SPH];               // 65.7 KiB fp16 pd rows
    __shared__ __align__(16) float s_qT[TQ][CC];   // 4 KiB, [q][c] for phase 3
    __shared__ float s_sv[TQ][64];                 // survivor values (4 KiB)
    __shared__ int   s_si[TQ][64];                 // survivor indices (4 KiB)

    int tid = threadIdx.x;
    int b = blockIdx.x >> 7;                       // NN/TQ = 128 blocks/batch
    int n0 = (blockIdx.x & 127) * TQ;
    const float* xb = x + (size_t)b * CC * NN;

    {
        int c = tid >> 4, qq = tid & 15;
        s_qT[qq][c] = xb[c * NN + n0 + qq];
    }
    __syncthreads();

    // ---- phase 1: fill (thread owns 2 consecutive m for all 16 queries) ----
    {
        float xxn[TQ];
#pragma unroll
        for (int i = 0; i < TQ; i += 4) {
            float4 t = *(const float4*)(xxf + b * NN + n0 + i);   // uniform -> s_load
            xxn[i] = t.x; xxn[i + 1] = t.y; xxn[i + 2] = t.z; xxn[i + 3] = t.w;
        }

        int m = tid * 2;
        float acc[TQ][2];
#pragma unroll
        for (int q = 0; q < TQ; ++q) { acc[q][0] = 0.f; acc[q][1] = 0.f; }

        for (int c = 0; c < CC; ++c) {
            float2 xv = *(const float2*)(xb + c * NN + m);
            // wave-uniform address -> scalar loads (constant cache, no LDS)
            const float* qp = xb + c * NN + n0;
            float qs[TQ];
#pragma unroll
            for (int i = 0; i < TQ; i += 4) {
                float4 t = *(const float4*)(qp + i);
                qs[i] = t.x; qs[i + 1] = t.y; qs[i + 2] = t.z; qs[i + 3] = t.w;
            }
#pragma unroll
            for (int q = 0; q < TQ; ++q) {
                acc[q][0] += qs[q] * xv.x;
                acc[q][1] += qs[q] * xv.y;
            }
        }
        float2 xm2 = *(const float2*)(xxf + b * NN + m);
#pragma unroll
        for (int q = 0; q < TQ; ++q) {
            float p0 = (2.f * acc[q][0] - xxn[q]) - xm2.x;
            float p1 = (2.f * acc[q][1] - xxn[q]) - xm2.y;
            *(__half2*)(&s_pd[q][m]) = __floats2half2_rn(p0, p1);
        }
    }
    __syncthreads();

    // ---- phase 2: per-wave selection ----
    int q = tid >> 6;
    int lane = tid & 63;
    const __half* pd = &s_pd[q][0];

    float v[32];
#pragma unroll
    for (int r = 0; r < 32; ++r) v[r] = __half2float(pd[lane + (r << 6)]);

    float lmax = v[0]; int lr = 0;
#pragma unroll
    for (int r = 1; r < 32; ++r)
        if (v[r] > lmax) { lmax = v[r]; lr = r; }              // strict > : lowest idx

    // tau = 26th-largest lane-max (values-only 64-lane bitonic, descending)
    float sv = lmax;
#pragma unroll
    for (int k = 2; k <= 64; k <<= 1) {
#pragma unroll
        for (int j = k >> 1; j > 0; j >>= 1) {
            float o = __shfl_xor(sv, j);
            bool dird = ((lane & k) == 0);
            bool first = ((lane & j) == 0);
            sv = (first == dird) ? fmaxf(sv, o) : fminf(sv, o);
        }
    }
    float tau = __shfl(sv, 25);

    int cnt = 0;
#pragma unroll
    for (int r = 0; r < 32; ++r) cnt += (v[r] >= tau) ? 1 : 0;
    int incl = cnt;
#pragma unroll
    for (int off = 1; off < 64; off <<= 1) {
        int o = __shfl_up(incl, off);
        if (lane >= off) incl += o;
    }
    int S = __shfl(incl, 63);

    float fv = -INFINITY;
    int fi = 0x7fffffff;
    if (S <= 64) {
        int w = incl - cnt;
#pragma unroll
        for (int r = 0; r < 32; ++r) {
            if (v[r] >= tau) { s_sv[q][w] = v[r]; s_si[q][w] = lane + (r << 6); ++w; }
        }
        if (lane < S) { fv = s_sv[q][lane]; fi = s_si[q][lane]; }
    } else {
        // pathological (mass ties): exact iterative top-26 extraction
        for (int t = 0; t < NC; ++t) {
            float bv = lmax; int bi = lane + (lr << 6);
#pragma unroll
            for (int off = 32; off; off >>= 1) {
                float ov = __shfl_xor(bv, off);
                int oi = __shfl_xor(bi, off);
                if (ov > bv || (ov == bv && oi < bi)) { bv = ov; bi = oi; }
            }
            if (lane == t) { fv = bv; fi = bi; }
            if ((bi & 63) == lane) {
                int rsel = bi >> 6;
#pragma unroll
                for (int r = 0; r < 32; ++r) if (r == rsel) v[r] = -INFINITY;
                lmax = v[0]; lr = 0;
#pragma unroll
                for (int r = 1; r < 32; ++r)
                    if (v[r] > lmax) { lmax = v[r]; lr = r; }
            }
        }
    }

    // 64-lane bitonic sort of (fv desc, fi asc) -> lanes 0..25 = approx top-26
#pragma unroll
    for (int k = 2; k <= 64; k <<= 1) {
#pragma unroll
        for (int j = k >> 1; j > 0; j >>= 1) {
            float ov = __shfl_xor(fv, j);
            int oi = __shfl_xor(fi, j);
            bool dird = ((lane & k) == 0);
            bool first = ((lane & j) == 0);
            bool better = (fv > ov) || (fv == ov && fi < oi);
            if (better != (first == dird)) { fv = ov; fi = oi; }
        }
    }

    // ---- phase 3: fp64 refine (direct global candidate rows, L2-hot) ----
    int nq = n0 + q;
    double accd = 0.0;
    if (lane < NC) {
        const float* crow = xt + (size_t)b * NN * CC + (size_t)fi * CC;
        const float* qrow = &s_qT[q][0];
        double a0 = 0.0, a1 = 0.0, a2 = 0.0, a3 = 0.0;
#pragma unroll
        for (int j = 0; j < 16; ++j) {
            float4 cv = *(const float4*)(crow + j * 4);
            float4 qv = *(const float4*)(qrow + j * 4);   // LDS b128 broadcast
            a0 = fma((double)qv.x, (double)cv.x, a0);
            a1 = fma((double)qv.y, (double)cv.y, a1);
            a2 = fma((double)qv.z, (double)cv.z, a2);
            a3 = fma((double)qv.w, (double)cv.w, a3);
        }
        accd = (a0 + a1) + (a2 + a3);
    }

    double val = -INFINITY;
    int idxq = 0x7fffffff;
    if (lane < NC) {
        val = 2.0 * accd - xxd[b * NN + nq] - xxd[b * NN + fi];
        idxq = fi;
    }

    // 32-lane fp64 bitonic (val desc, idx asc)
#pragma unroll
    for (int k = 2; k <= 32; k <<= 1) {
#pragma unroll
        for (int j = k >> 1; j > 0; j >>= 1) {
            double ov = __shfl_xor(val, j, 32);
            int oi = __shfl_xor(idxq, j, 32);
            bool dird = ((lane & k) == 0);
            bool first = ((lane & j) == 0);
            bool better = (val > ov) || (val == ov && idxq < oi);
            if (better != (first == dird)) { val = ov; idxq = oi; }
        }
    }

    if (lane < KK) {
        size_t obase = ((size_t)b * NN + nq) * KK;
        idx_ws[obase + lane] = idxq;
        idx_out[obase + lane] = (float)(idxq + b * NN);
        s_si[q][lane] = idxq;                      // stash top-20 for fused x1
    }

    // ---- fused x1: per-channel mean of top-14 of the 20 neighbor values ----
    {
        const float* xtb = xt + (size_t)b * NN * CC;
        float vals[KK];
        float sum = 0.f;
#pragma unroll
        for (int j = 0; j < KK; ++j) {
            int ij = s_si[q][j];                   // per-wave LDS broadcast
            vals[j] = xtb[(size_t)ij * CC + lane]; // lane c reads channel c
            sum += vals[j];
        }
#pragma unroll
        for (int t = 0; t < KK - K2; ++t) {
            float worst = INFINITY;
            int wj = 0;
#pragma unroll
            for (int j = 0; j < KK; ++j)
                if (vals[j] < worst) { worst = vals[j]; wj = j; }
            sum -= worst;
#pragma unroll
            for (int j = 0; j < KK; ++j)
                if (j == wj) vals[j] = INFINITY;
        }
        x1t[((size_t)b * CC + lane) * NN + nq] = sum / (float)K2;
    }
}

// ---------------------------------------------------------------------------
// feat v2: ch<64 blocks stage the 8KB x1t row in LDS first (coalesced load),
// then gather from LDS. 64-lane random gathers in L1 serialize on distinct
// cache lines (~40-60cy/instr, the measured ~130us vs ~56us write floor);
// random LDS reads average ~2 lanes/bank = conflict-free (m136).
// Write-only 335 MB output -> non-temporal stores.
// ---------------------------------------------------------------------------
__global__ __launch_bounds__(256) void feat_kernel(const float* __restrict__ x,
                                                   const float* __restrict__ x1t,
                                                   const int* __restrict__ idx_ws,
                                                   float* __restrict__ out) {
    __shared__ float s_row[NN];                    // 8 KiB
    int bc = blockIdx.x;
    int b = bc >> 7, ch = bc & 127;
    const float* xb = x + (size_t)b * CC * NN;
    float* o = out + (size_t)bc * NN * KK;
    const int* idxb = idx_ws + (size_t)b * NN * KK;

    if (ch < CC) {
        const float* row = x1t + ((size_t)b * CC + ch) * NN;
        const float* xr = xb + ch * NN;
        // stage row -> LDS (coalesced, 2 float4 per thread)
        {
            int t4 = threadIdx.x * 4;
            *(float4*)(&s_row[t4]) = *(const float4*)(row + t4);
            *(float4*)(&s_row[t4 + 1024]) = *(const float4*)(row + t4 + 1024);
        }
        __syncthreads();
        for (int it = 0; it < 40; ++it) {
            unsigned e = (it * 256 + threadIdx.x) * 4;
            int4 id4 = *(const int4*)(idxb + e);
            nfloat4 o4;
            o4.x = s_row[id4.x] - xr[(e    ) / KK];
            o4.y = s_row[id4.y] - xr[(e + 1) / KK];
            o4.z = s_row[id4.z] - xr[(e + 2) / KK];
            o4.w = s_row[id4.w] - xr[(e + 3) / KK];
            __builtin_nontemporal_store(o4, (nfloat4*)(o + e));
        }
    } else {
        const float* xr = xb + (ch - CC) * NN;
        for (int it = 0; it < 40; ++it) {
            unsigned e = (it * 256 + threadIdx.x) * 4;
            nfloat4 o4;
            o4.x = xr[(e    ) / KK];
            o4.y = xr[(e + 1) / KK];
            o4.z = xr[(e + 2) / KK];
            o4.w = xr[(e + 3) / KK];
            __builtin_nontemporal_store(o4, (nfloat4*)(o + e));
        }
    }
}

// ---------------------------------------------------------------------------
extern "C" void kernel_launch(void* const* d_in, const int* in_sizes, int n_in,
                              void* d_out, int out_size, void* d_ws, size_t ws_size,
                              hipStream_t stream) {
    const float* x = (const float*)d_in[0];   // (B, C, N) fp32
    float* out = (float*)d_out;

    char* ws = (char*)d_ws;
    float* xt   = (float*)ws;                                   // B*N*C
    float* x1t  = (float*)(ws + (size_t)8388608);               // B*C*N
    double* xxd = (double*)(ws + (size_t)16777216);             // B*N
    float* xxf  = (float*)(ws + (size_t)17039360);              // B*N
    int* idx_ws = (int*)(ws + (size_t)17170432);                // B*N*K

    float* idx_out = out + (size_t)BB * 2 * CC * NN * KK;       // idx_flat tail

    prep_kernel<<<BB * (NN / 64), 256, 0, stream>>>(x, xt, xxf, xxd);
    knn_kernel<<<BB * (NN / TQ), 1024, 0, stream>>>(x, xt, xxf, xxd, idx_ws, idx_out, x1t);
    feat_kernel<<<BB * 2 * CC, 256, 0, stream>>>(x, x1t, idx_ws, out);
}